// Round 1
// baseline (114.846 us; speedup 1.0000x reference)
//
#include <hip/hip_runtime.h>
#include <stdint.h>

#define Bb 8
#define Ll 2048
#define Ss 2048
#define Dd 128
#define NSB 8
#define SCHUNK 256
#define NROWS 16384  // Bb*Ll == Bb*Ss
#define SCALE_LOG2E 92.33248261689366f  // 64 * log2(e); also the fixed softmax max

typedef __attribute__((ext_vector_type(8))) short bf16x8;
typedef __attribute__((ext_vector_type(16))) float f32x16;

__device__ __forceinline__ unsigned f2bf_pack(float a, float b) {
  unsigned ua = __float_as_uint(a); ua += 0x7fffu + ((ua >> 16) & 1u);
  unsigned ub = __float_as_uint(b); ub += 0x7fffu + ((ub >> 16) & 1u);
  return (ua >> 16) | (ub & 0xffff0000u);
}

__device__ __forceinline__ unsigned pkbf(float a, float b) {
#if __has_builtin(__builtin_amdgcn_cvt_pk_bf16_f32)
  auto r = __builtin_amdgcn_cvt_pk_bf16_f32(a, b);
  return __builtin_bit_cast(unsigned, r);
#else
  return f2bf_pack(a, b);
#endif
}

__device__ __forceinline__ void gl_lds16(const void* g, void* l) {
  __builtin_amdgcn_global_load_lds(
      (const __attribute__((address_space(1))) unsigned*)g,
      (__attribute__((address_space(3))) unsigned*)l, 16, 0, 0);
}

// Fragment-major layouts, per 32-s block = 8 slots * 1 KB = 8 KB (4096 ushort):
//  Kf slot kt, lane l=(h*32+s): K[s][d=kt*16+h*8+j], j=0..7
//  Vf slot (dblk*2+t2), lane l=(h*32+dloc): V^T[d=dblk*32+dloc][s_perm]
//    s_perm = t2*16 + 4*h + (j&3) + 8*(j>>2)  == S-MFMA C-reg order, so the
//    P B-fragment is just consecutive acc registers (no shuffles).

// ---------------- pre-pass (identical to prior rounds, verified) ----------------
extern "C" __global__ __launch_bounds__(256)
void prep_kern(const float* __restrict__ Q, const float* __restrict__ K,
               const float* __restrict__ V,
               unsigned short* __restrict__ Qn, unsigned short* __restrict__ Kf,
               unsigned short* __restrict__ Vf) {
  __shared__ float Tf[32 * 130];
  __shared__ float Ps[32 * 8];
  __shared__ float Nr[32];
  __shared__ unsigned short Tb[32 * 128];
  const int t = threadIdx.x;
  const int bid = blockIdx.x;
  if (bid < 4096) {  // Q: one row per wave, row-major bf16 out
    const int lane = t & 63;
    const int r = bid * 4 + (t >> 6);
    float2 f = *(const float2*)(Q + (size_t)r * Dd + lane * 2);
    float ss = f.x * f.x + f.y * f.y;
#pragma unroll
    for (int m = 1; m < 64; m <<= 1) ss += __shfl_xor(ss, m, 64);
    float inv = 1.0f / fmaxf(sqrtf(ss), 1e-12f);
    *(unsigned*)(Qn + (size_t)r * Dd + lane * 2) = pkbf(f.x * inv, f.y * inv);
  } else if (bid < 4608) {  // K: 32-row block -> normalize -> frag-major
    const int kb = bid - 4096;
    const int b = kb & 7, sw = kb >> 3;
    const int sl = t >> 3, d0 = (t & 7) * 16;
    const float* src = K + ((size_t)(b * Ss + sw * 32 + sl)) * Dd + d0;
    float ss = 0.f;
#pragma unroll
    for (int i = 0; i < 4; ++i) {
      float4 v = *(const float4*)(src + i * 4);
      Tf[sl * 130 + d0 + i * 4 + 0] = v.x;
      Tf[sl * 130 + d0 + i * 4 + 1] = v.y;
      Tf[sl * 130 + d0 + i * 4 + 2] = v.z;
      Tf[sl * 130 + d0 + i * 4 + 3] = v.w;
      ss += v.x * v.x + v.y * v.y + v.z * v.z + v.w * v.w;
    }
    Ps[sl * 8 + (t & 7)] = ss;
    __syncthreads();
    if (t < 32) {
      float s = 0.f;
#pragma unroll
      for (int j = 0; j < 8; ++j) s += Ps[t * 8 + j];
      Nr[t] = 1.0f / fmaxf(sqrtf(s), 1e-12f);
    }
    __syncthreads();
    unsigned short* Ko = Kf + ((size_t)(b * 64 + sw)) * 4096;
#pragma unroll
    for (int p = 0; p < 2; ++p) {
      const int run = p * 256 + t;
      const int lane = run & 63, s = lane & 31, h = lane >> 5;
      const int d = (run >> 6) * 16 + h * 8;
      const float n = Nr[s];
      const float* row = &Tf[s * 130 + d];
      uint4 w;
      w.x = pkbf(row[0] * n, row[1] * n);
      w.y = pkbf(row[2] * n, row[3] * n);
      w.z = pkbf(row[4] * n, row[5] * n);
      w.w = pkbf(row[6] * n, row[7] * n);
      *(uint4*)(Ko + run * 8) = w;
    }
  } else {  // V: 32-row block -> transpose -> j-permuted frag-major
    const int vb = bid - 4608;
    const int b = vb & 7, sw = vb >> 3;
    const int sl = t >> 3, d0 = (t & 7) * 16;
    const float* src = V + ((size_t)(b * Ss + sw * 32 + sl)) * Dd + d0;
#pragma unroll
    for (int i = 0; i < 4; ++i) {
      float4 v = *(const float4*)(src + i * 4);
      *(unsigned*)&Tb[sl * 128 + d0 + i * 4]     = pkbf(v.x, v.y);
      *(unsigned*)&Tb[sl * 128 + d0 + i * 4 + 2] = pkbf(v.z, v.w);
    }
    __syncthreads();
    unsigned short* Vo = Vf + ((size_t)(b * 64 + sw)) * 4096;
#pragma unroll
    for (int p = 0; p < 2; ++p) {
      const int run = p * 256 + t;
      const int vslot = run >> 6, lane = run & 63;
      const int dloc = lane & 31, h = lane >> 5;
      const int dblk = vslot >> 1, t2 = vslot & 1;
      const int d = dblk * 32 + dloc;
      unsigned short w[8];
#pragma unroll
      for (int j = 0; j < 8; ++j) {
        const int sloc = t2 * 16 + 4 * h + (j & 3) + 8 * (j >> 2);
        w[j] = Tb[sloc * 128 + d];
      }
      *(uint4*)(Vo + run * 8) = *(uint4*)w;
    }
  }
}

// ---------------- main fused attention: q64/wave, vmcnt-gated ring pipeline ----
// grid 512: gid = sb*64 + qt*8 + b (KV sharers AND partial groups colocate per
// XCD). 4 waves x 64 q-rows = 256 rows/block; SCHUNK=256 -> 8 iters of 32-s.
// Both S-chains share each K fragment; both P-halves share each V fragment:
// LDS reads per iter stay at 16x ds_read_b128 while MFMAs double to 32
// (flips per-CU balance from LDS-read-bound to MFMA-bound).
// 4-deep LDS ring (64 KB), staged at distance 2; per-iter gate =
// `s_waitcnt vmcnt(4); s_barrier` so the barrier never drains prefetches.
extern "C" __global__ __launch_bounds__(256, 2)
void attn_kern(const unsigned short* __restrict__ Qn,
               const unsigned short* __restrict__ Kf,
               const unsigned short* __restrict__ Vf,
               unsigned short* __restrict__ Op,
               float* __restrict__ Lp) {
  __shared__ unsigned short Kl[4][8 * 512];  // 4-ring of 8-slot (8 KB) K tiles
  __shared__ unsigned short Vl[4][8 * 512];
  const int tid = threadIdx.x, wv = tid >> 6, lane = tid & 63;
  const int lm = lane & 31, h = lane >> 5;
  const int gid = blockIdx.x;
  const int sb = gid >> 6, qt = (gid >> 3) & 7, b = gid & 7;
  const int qrow0 = qt * 256 + wv * 64;  // first of this wave's 64 q-rows

  // Q B-fragments (k = d): 16 frags = 64 VGPR, resident for whole kernel
  bf16x8 qf[16];
#pragma unroll
  for (int mh = 0; mh < 2; ++mh) {
    const unsigned short* Qrow =
        Qn + ((size_t)(b * Ll + qrow0 + mh * 32 + lm)) * Dd;
#pragma unroll
    for (int kt = 0; kt < 8; ++kt)
      qf[mh * 8 + kt] = *(const bf16x8*)(Qrow + kt * 16 + h * 8);
  }

  const unsigned short* Kc = Kf + ((size_t)(b * 64 + sb * 8)) * 4096;
  const unsigned short* Vc = Vf + ((size_t)(b * 64 + sb * 8)) * 4096;

  f32x16 o[8];
#pragma unroll
  for (int i = 0; i < 8; ++i)
#pragma unroll
    for (int r = 0; r < 16; ++r) o[i][r] = 0.f;

  // stage tile t into ring slot r: 4 gl_lds16 per wave (2 K + 2 V)
  auto stage = [&](int t, int r) {
    const unsigned short* kb = Kc + (size_t)t * 4096;
    const unsigned short* vb = Vc + (size_t)t * 4096;
#pragma unroll
    for (int i = 0; i < 2; ++i) {
      const int sl = wv * 2 + i;
      gl_lds16(kb + sl * 512 + lane * 8, &Kl[r][sl * 512]);
      gl_lds16(vb + sl * 512 + lane * 8, &Vl[r][sl * 512]);
    }
  };
  stage(0, 0);
  stage(1, 1);

  float lr0 = 0.f, lr1 = 0.f;

#pragma unroll 1
  for (int it = 0; it < 8; ++it) {
    // Gate: batch(it) complete (<=4 outstanding leaves only batch(it+1)
    // in flight), then converge. No vmcnt(0) drain except the final tile.
    if (it < 7)
      asm volatile("s_waitcnt vmcnt(4)\n\ts_barrier" ::: "memory");
    else
      asm volatile("s_waitcnt vmcnt(0)\n\ts_barrier" ::: "memory");
    const int r = it & 3;
    if (it + 2 < 8) stage(it + 2, (it + 2) & 3);

    // S^T = K · Q^T for both m-halves; each kf feeds two MFMAs
    f32x16 a0, a1;
#pragma unroll
    for (int rr = 0; rr < 16; ++rr) { a0[rr] = 0.f; a1[rr] = 0.f; }
    __builtin_amdgcn_s_setprio(1);
#pragma unroll
    for (int kt = 0; kt < 8; ++kt) {
      bf16x8 kf = *(const bf16x8*)&Kl[r][kt * 512 + lane * 8];
      a0 = __builtin_amdgcn_mfma_f32_32x32x16_bf16(kf, qf[kt], a0, 0, 0, 0);
      a1 = __builtin_amdgcn_mfma_f32_32x32x16_bf16(kf, qf[8 + kt], a1, 0, 0, 0);
    }
    __builtin_amdgcn_s_setprio(0);

    // fixed-max softmax; P B-frags = consecutive acc regs (j-permuted Vf)
    uint4 pf0[2], pf1[2];
#pragma unroll
    for (int t2 = 0; t2 < 2; ++t2) {
      float p[8], q[8];
#pragma unroll
      for (int j = 0; j < 8; ++j) {
        p[j] = __builtin_amdgcn_exp2f(
            __builtin_fmaf(a0[t2 * 8 + j], SCALE_LOG2E, -SCALE_LOG2E));
        q[j] = __builtin_amdgcn_exp2f(
            __builtin_fmaf(a1[t2 * 8 + j], SCALE_LOG2E, -SCALE_LOG2E));
      }
      lr0 += ((p[0] + p[1]) + (p[2] + p[3])) + ((p[4] + p[5]) + (p[6] + p[7]));
      lr1 += ((q[0] + q[1]) + (q[2] + q[3])) + ((q[4] + q[5]) + (q[6] + q[7]));
      pf0[t2].x = pkbf(p[0], p[1]);
      pf0[t2].y = pkbf(p[2], p[3]);
      pf0[t2].z = pkbf(p[4], p[5]);
      pf0[t2].w = pkbf(p[6], p[7]);
      pf1[t2].x = pkbf(q[0], q[1]);
      pf1[t2].y = pkbf(q[2], q[3]);
      pf1[t2].z = pkbf(q[4], q[5]);
      pf1[t2].w = pkbf(q[6], q[7]);
    }

    // O^T += V^T · P^T; each vf feeds two MFMAs (one per m-half)
    __builtin_amdgcn_s_setprio(1);
#pragma unroll
    for (int t2 = 0; t2 < 2; ++t2) {
#pragma unroll
      for (int dblk = 0; dblk < 4; ++dblk) {
        bf16x8 vf = *(const bf16x8*)&Vl[r][(dblk * 2 + t2) * 512 + lane * 8];
        o[dblk] = __builtin_amdgcn_mfma_f32_32x32x16_bf16(
            vf, __builtin_bit_cast(bf16x8, pf0[t2]), o[dblk], 0, 0, 0);
        o[4 + dblk] = __builtin_amdgcn_mfma_f32_32x32x16_bf16(
            vf, __builtin_bit_cast(bf16x8, pf1[t2]), o[4 + dblk], 0, 0, 0);
      }
    }
    __builtin_amdgcn_s_setprio(0);
  }

  // epilogue: partial (unnormalized) O bf16 + per-row l (shared fixed max)
#pragma unroll
  for (int mh = 0; mh < 2; ++mh) {
    const float lrm = mh ? lr1 : lr0;
    const float lt = lrm + __shfl_xor(lrm, 32, 64);
    const int qr = qrow0 + mh * 32 + lm;
    unsigned short* Ob = Op + ((size_t)sb * NROWS + b * Ll + qr) * Dd;
#pragma unroll
    for (int dblk = 0; dblk < 4; ++dblk)
#pragma unroll
      for (int g = 0; g < 4; ++g) {
        uint2 w;
        w.x = pkbf(o[mh * 4 + dblk][g * 4 + 0], o[mh * 4 + dblk][g * 4 + 1]);
        w.y = pkbf(o[mh * 4 + dblk][g * 4 + 2], o[mh * 4 + dblk][g * 4 + 3]);
        *(uint2*)(Ob + dblk * 32 + g * 8 + h * 4) = w;  // d = 32*dblk+8*g+4*h
      }
    if (h == 0) Lp[(size_t)sb * NROWS + b * Ll + qr] = lt;
  }
}

// ---------------- combine the NSB S-chunk partials (pure sum: shared max) ---
extern "C" __global__ __launch_bounds__(256)
void comb_kern(const unsigned short* __restrict__ Op,
               const float* __restrict__ Lp, float* __restrict__ Out) {
  const int idx = blockIdx.x * 256 + threadIdx.x;  // one thread per 4 d
  const int row = idx >> 5;
  const int dof = (idx & 31) * 4;
  float den = 0.f;
#pragma unroll
  for (int s = 0; s < NSB; ++s) den += Lp[(size_t)s * NROWS + row];
  float a0 = 0.f, a1 = 0.f, a2 = 0.f, a3 = 0.f;
#pragma unroll
  for (int s = 0; s < NSB; ++s) {
    uint2 v = *(const uint2*)(Op + ((size_t)s * NROWS + row) * Dd + dof);
    a0 += __uint_as_float(v.x << 16);
    a1 += __uint_as_float(v.x & 0xffff0000u);
    a2 += __uint_as_float(v.y << 16);
    a3 += __uint_as_float(v.y & 0xffff0000u);
  }
  const float inv = 1.f / den;
  float4 r; r.x = a0 * inv; r.y = a1 * inv; r.z = a2 * inv; r.w = a3 * inv;
  *(float4*)(Out + (size_t)row * Dd + dof) = r;
}

extern "C" void kernel_launch(void* const* d_in, const int* in_sizes, int n_in,
                              void* d_out, int out_size, void* d_ws, size_t ws_size,
                              hipStream_t stream) {
  const float* Q = (const float*)d_in[0];
  const float* K = (const float*)d_in[1];
  const float* V = (const float*)d_in[2];
  float* Out = (float*)d_out;
  unsigned short* Qn = (unsigned short*)d_ws;                  // 4 MiB
  unsigned short* Kf = Qn + (size_t)NROWS * Dd;                // 4 MiB (frag-major)
  unsigned short* Vf = Kf + (size_t)NROWS * Dd;                // 4 MiB (frag-major, j-permuted)
  unsigned short* Op = Vf + (size_t)Bb * Dd * Ss;              // 32 MiB (bf16 partials)
  float* Lp = (float*)(Op + (size_t)NSB * NROWS * Dd);         // 512 KiB
  hipLaunchKernelGGL(prep_kern, dim3(4096 + 512 + 512), dim3(256), 0, stream,
                     Q, K, V, Qn, Kf, Vf);
  hipLaunchKernelGGL(attn_kern, dim3(512), dim3(256), 0, stream, Qn, Kf, Vf, Op, Lp);
  hipLaunchKernelGGL(comb_kern, dim3(2048), dim3(256), 0, stream, Op, Lp, Out);
}

// Round 2
// 112.041 us; speedup vs baseline: 1.0250x; 1.0250x over previous
//
#include <hip/hip_runtime.h>
#include <stdint.h>

#define Bb 8
#define Ll 2048
#define Ss 2048
#define Dd 128
#define NSB 4
#define SCHUNK 512
#define NROWS 16384  // Bb*Ll == Bb*Ss
#define SCALE_LOG2E 92.33248261689366f  // 64 * log2(e); also the fixed softmax max

typedef __attribute__((ext_vector_type(8))) short bf16x8;
typedef __attribute__((ext_vector_type(16))) float f32x16;

__device__ __forceinline__ unsigned f2bf_pack(float a, float b) {
  unsigned ua = __float_as_uint(a); ua += 0x7fffu + ((ua >> 16) & 1u);
  unsigned ub = __float_as_uint(b); ub += 0x7fffu + ((ub >> 16) & 1u);
  return (ua >> 16) | (ub & 0xffff0000u);
}

__device__ __forceinline__ unsigned pkbf(float a, float b) {
#if __has_builtin(__builtin_amdgcn_cvt_pk_bf16_f32)
  auto r = __builtin_amdgcn_cvt_pk_bf16_f32(a, b);
  return __builtin_bit_cast(unsigned, r);
#else
  return f2bf_pack(a, b);
#endif
}

__device__ __forceinline__ void gl_lds16(const void* g, void* l) {
  __builtin_amdgcn_global_load_lds(
      (const __attribute__((address_space(1))) unsigned*)g,
      (__attribute__((address_space(3))) unsigned*)l, 16, 0, 0);
}

// Fragment-major layouts, per 32-s block = 8 slots * 1 KB = 8 KB (4096 ushort):
//  Kf slot kt, lane l=(h*32+s): K[s][d=kt*16+h*8+j], j=0..7
//  Vf slot (dblk*2+t2), lane l=(h*32+dloc): V^T[d=dblk*32+dloc][s_perm]
//    s_perm = t2*16 + 4*h + (j&3) + 8*(j>>2)  == S-MFMA C-reg order, so the
//    P B-fragment is just consecutive acc registers (no shuffles).

// ---------------- pre-pass (identical to prior rounds, verified) ----------------
extern "C" __global__ __launch_bounds__(256)
void prep_kern(const float* __restrict__ Q, const float* __restrict__ K,
               const float* __restrict__ V,
               unsigned short* __restrict__ Qn, unsigned short* __restrict__ Kf,
               unsigned short* __restrict__ Vf) {
  __shared__ float Tf[32 * 130];
  __shared__ float Ps[32 * 8];
  __shared__ float Nr[32];
  __shared__ unsigned short Tb[32 * 128];
  const int t = threadIdx.x;
  const int bid = blockIdx.x;
  if (bid < 4096) {  // Q: one row per wave, row-major bf16 out
    const int lane = t & 63;
    const int r = bid * 4 + (t >> 6);
    float2 f = *(const float2*)(Q + (size_t)r * Dd + lane * 2);
    float ss = f.x * f.x + f.y * f.y;
#pragma unroll
    for (int m = 1; m < 64; m <<= 1) ss += __shfl_xor(ss, m, 64);
    float inv = 1.0f / fmaxf(sqrtf(ss), 1e-12f);
    *(unsigned*)(Qn + (size_t)r * Dd + lane * 2) = pkbf(f.x * inv, f.y * inv);
  } else if (bid < 4608) {  // K: 32-row block -> normalize -> frag-major
    const int kb = bid - 4096;
    const int b = kb & 7, sw = kb >> 3;
    const int sl = t >> 3, d0 = (t & 7) * 16;
    const float* src = K + ((size_t)(b * Ss + sw * 32 + sl)) * Dd + d0;
    float ss = 0.f;
#pragma unroll
    for (int i = 0; i < 4; ++i) {
      float4 v = *(const float4*)(src + i * 4);
      Tf[sl * 130 + d0 + i * 4 + 0] = v.x;
      Tf[sl * 130 + d0 + i * 4 + 1] = v.y;
      Tf[sl * 130 + d0 + i * 4 + 2] = v.z;
      Tf[sl * 130 + d0 + i * 4 + 3] = v.w;
      ss += v.x * v.x + v.y * v.y + v.z * v.z + v.w * v.w;
    }
    Ps[sl * 8 + (t & 7)] = ss;
    __syncthreads();
    if (t < 32) {
      float s = 0.f;
#pragma unroll
      for (int j = 0; j < 8; ++j) s += Ps[t * 8 + j];
      Nr[t] = 1.0f / fmaxf(sqrtf(s), 1e-12f);
    }
    __syncthreads();
    unsigned short* Ko = Kf + ((size_t)(b * 64 + sw)) * 4096;
#pragma unroll
    for (int p = 0; p < 2; ++p) {
      const int run = p * 256 + t;
      const int lane = run & 63, s = lane & 31, h = lane >> 5;
      const int d = (run >> 6) * 16 + h * 8;
      const float n = Nr[s];
      const float* row = &Tf[s * 130 + d];
      uint4 w;
      w.x = pkbf(row[0] * n, row[1] * n);
      w.y = pkbf(row[2] * n, row[3] * n);
      w.z = pkbf(row[4] * n, row[5] * n);
      w.w = pkbf(row[6] * n, row[7] * n);
      *(uint4*)(Ko + run * 8) = w;
    }
  } else {  // V: 32-row block -> transpose -> j-permuted frag-major
    const int vb = bid - 4608;
    const int b = vb & 7, sw = vb >> 3;
    const int sl = t >> 3, d0 = (t & 7) * 16;
    const float* src = V + ((size_t)(b * Ss + sw * 32 + sl)) * Dd + d0;
#pragma unroll
    for (int i = 0; i < 4; ++i) {
      float4 v = *(const float4*)(src + i * 4);
      *(unsigned*)&Tb[sl * 128 + d0 + i * 4]     = pkbf(v.x, v.y);
      *(unsigned*)&Tb[sl * 128 + d0 + i * 4 + 2] = pkbf(v.z, v.w);
    }
    __syncthreads();
    unsigned short* Vo = Vf + ((size_t)(b * 64 + sw)) * 4096;
#pragma unroll
    for (int p = 0; p < 2; ++p) {
      const int run = p * 256 + t;
      const int vslot = run >> 6, lane = run & 63;
      const int dloc = lane & 31, h = lane >> 5;
      const int dblk = vslot >> 1, t2 = vslot & 1;
      const int d = dblk * 32 + dloc;
      unsigned short w[8];
#pragma unroll
      for (int j = 0; j < 8; ++j) {
        const int sloc = t2 * 16 + 4 * h + (j & 3) + 8 * (j >> 2);
        w[j] = Tb[sloc * 128 + d];
      }
      *(uint4*)(Vo + run * 8) = *(uint4*)w;
    }
  }
}

// ---------------- main fused attention: 2-wave blocks, 4 independent
// pipelines per CU. grid 1024: gid = qt*32 + b*4 + sb (all 32 qt-sharers of a
// (b,sb) K/V chunk land on one XCD: gid%8 = (b*4+sb)%8). Each wave owns 32
// q-rows; q32 math identical to the verified 106.6 baseline. 2-deep LDS ring
// (32 KB/block): gate = `s_waitcnt vmcnt(8); s_barrier` (counted, never
// drains the in-flight batch); staging at distance 2 sits AFTER a raw
// `lgkmcnt(0); s_barrier` (all waves' ds_reads of the slot complete — raw
// barrier, NOT __syncthreads, which would emit vmcnt(0) and drain the ring).
extern "C" __global__ __launch_bounds__(128, 2)
void attn_kern(const unsigned short* __restrict__ Qn,
               const unsigned short* __restrict__ Kf,
               const unsigned short* __restrict__ Vf,
               unsigned short* __restrict__ Op,
               float* __restrict__ Lp) {
  __shared__ unsigned short Kl[2][8 * 512];  // 2-ring of 8-slot (8 KB) K tiles
  __shared__ unsigned short Vl[2][8 * 512];
  const int tid = threadIdx.x, wv = tid >> 6, lane = tid & 63;
  const int lm = lane & 31, h = lane >> 5;
  const int gid = blockIdx.x;
  const int qt = gid >> 5, b = (gid >> 2) & 7, sb = gid & 3;
  const int qrow = qt * 64 + wv * 32 + lm;

  // Q B-fragments (k = d): registers for whole kernel (oldest vmem ops)
  const unsigned short* Qrow = Qn + ((size_t)(b * Ll + qrow)) * Dd;
  bf16x8 qf[8];
#pragma unroll
  for (int kt = 0; kt < 8; ++kt)
    qf[kt] = *(const bf16x8*)(Qrow + kt * 16 + h * 8);

  const unsigned short* Kc = Kf + ((size_t)(b * 64 + sb * 16)) * 4096;
  const unsigned short* Vc = Vf + ((size_t)(b * 64 + sb * 16)) * 4096;

  f32x16 o[4];
#pragma unroll
  for (int i = 0; i < 4; ++i)
#pragma unroll
    for (int r = 0; r < 16; ++r) o[i][r] = 0.f;

  // stage tile t into ring slot r: 8 gl_lds16 per wave (4 K + 4 V)
  auto stage = [&](int t, int r) {
    const unsigned short* kb = Kc + (size_t)t * 4096;
    const unsigned short* vb = Vc + (size_t)t * 4096;
#pragma unroll
    for (int i = 0; i < 4; ++i) {
      const int sl = wv * 4 + i;
      gl_lds16(kb + sl * 512 + lane * 8, &Kl[r][sl * 512]);
      gl_lds16(vb + sl * 512 + lane * 8, &Vl[r][sl * 512]);
    }
  };
  stage(0, 0);
  stage(1, 1);

  float lrun = 0.f;

#pragma unroll 1
  for (int it = 0; it < 16; ++it) {
    // Gate: batch(it) complete. Outstanding at gate = batch(it)+batch(it+1)
    // (8 each per wave) -> vmcnt(8) waits exactly batch(it). Final tile has
    // only batch(15) in flight -> must drain with vmcnt(0).
    if (it < 15)
      asm volatile("s_waitcnt vmcnt(8)\n\ts_barrier" ::: "memory");
    else
      asm volatile("s_waitcnt vmcnt(0)\n\ts_barrier" ::: "memory");
    const int r = it & 1;

    // S^T = K · Q^T  (M=s 32, N=m 32, K=d 8x16)
    f32x16 acc;
#pragma unroll
    for (int rr = 0; rr < 16; ++rr) acc[rr] = 0.f;
    __builtin_amdgcn_s_setprio(1);
#pragma unroll
    for (int kt = 0; kt < 8; ++kt) {
      bf16x8 kf = *(const bf16x8*)&Kl[r][kt * 512 + lane * 8];
      acc = __builtin_amdgcn_mfma_f32_32x32x16_bf16(kf, qf[kt], acc, 0, 0, 0);
    }
    __builtin_amdgcn_s_setprio(0);
    // fixed-max softmax; P B-frag = consecutive acc regs (j-permuted Vf)
#pragma unroll
    for (int t2 = 0; t2 < 2; ++t2) {
      float p[8];
#pragma unroll
      for (int j = 0; j < 8; ++j)
        p[j] = __builtin_amdgcn_exp2f(
            __builtin_fmaf(acc[t2 * 8 + j], SCALE_LOG2E, -SCALE_LOG2E));
      lrun += ((p[0] + p[1]) + (p[2] + p[3])) + ((p[4] + p[5]) + (p[6] + p[7]));
      uint4 fr;
      fr.x = pkbf(p[0], p[1]);
      fr.y = pkbf(p[2], p[3]);
      fr.z = pkbf(p[4], p[5]);
      fr.w = pkbf(p[6], p[7]);
      bf16x8 pf = __builtin_bit_cast(bf16x8, fr);
      // O^T += V^T · P^T  (M=d 4x32, N=m 32, K=s 16, s-order pre-permuted)
      __builtin_amdgcn_s_setprio(1);
#pragma unroll
      for (int dblk = 0; dblk < 4; ++dblk) {
        bf16x8 vf = *(const bf16x8*)&Vl[r][(dblk * 2 + t2) * 512 + lane * 8];
        o[dblk] = __builtin_amdgcn_mfma_f32_32x32x16_bf16(vf, pf, o[dblk], 0, 0, 0);
      }
      __builtin_amdgcn_s_setprio(0);
    }

    // Stage tile it+2 into the slot just consumed. Raw barrier with
    // lgkmcnt(0) only: all waves' ds_reads of slot r are complete (their
    // consuming MFMAs already executed), and in-flight gl_lds prefetches
    // (vmcnt) stay outstanding.
    if (it + 2 < 16) {
      asm volatile("s_waitcnt lgkmcnt(0)\n\ts_barrier" ::: "memory");
      stage(it + 2, r);
    }
  }

  // epilogue: partial (unnormalized) O bf16 + per-row l (shared fixed max)
  const float lt = lrun + __shfl_xor(lrun, 32, 64);
  unsigned short* Ob = Op + ((size_t)sb * NROWS + b * Ll + qrow) * Dd;
#pragma unroll
  for (int dblk = 0; dblk < 4; ++dblk)
#pragma unroll
    for (int g = 0; g < 4; ++g) {
      uint2 w;
      w.x = pkbf(o[dblk][g * 4 + 0], o[dblk][g * 4 + 1]);
      w.y = pkbf(o[dblk][g * 4 + 2], o[dblk][g * 4 + 3]);
      *(uint2*)(Ob + dblk * 32 + g * 8 + h * 4) = w;  // d = 32*dblk + 8*g + 4*h
    }
  if (h == 0) Lp[sb * NROWS + b * Ll + qrow] = lt;
}

// ---------------- combine the NSB S-chunk partials (pure sum: shared max) ---
extern "C" __global__ __launch_bounds__(256)
void comb_kern(const unsigned short* __restrict__ Op,
               const float* __restrict__ Lp, float* __restrict__ Out) {
  const int idx = blockIdx.x * 256 + threadIdx.x;  // one thread per 4 d
  const int row = idx >> 5;
  const int dof = (idx & 31) * 4;
  float den = 0.f;
#pragma unroll
  for (int s = 0; s < NSB; ++s) den += Lp[s * NROWS + row];
  float a0 = 0.f, a1 = 0.f, a2 = 0.f, a3 = 0.f;
#pragma unroll
  for (int s = 0; s < NSB; ++s) {
    uint2 v = *(const uint2*)(Op + ((size_t)s * NROWS + row) * Dd + dof);
    a0 += __uint_as_float(v.x << 16);
    a1 += __uint_as_float(v.x & 0xffff0000u);
    a2 += __uint_as_float(v.y << 16);
    a3 += __uint_as_float(v.y & 0xffff0000u);
  }
  const float inv = 1.f / den;
  float4 r; r.x = a0 * inv; r.y = a1 * inv; r.z = a2 * inv; r.w = a3 * inv;
  *(float4*)(Out + (size_t)row * Dd + dof) = r;
}

extern "C" void kernel_launch(void* const* d_in, const int* in_sizes, int n_in,
                              void* d_out, int out_size, void* d_ws, size_t ws_size,
                              hipStream_t stream) {
  const float* Q = (const float*)d_in[0];
  const float* K = (const float*)d_in[1];
  const float* V = (const float*)d_in[2];
  float* Out = (float*)d_out;
  unsigned short* Qn = (unsigned short*)d_ws;                  // 4 MiB
  unsigned short* Kf = Qn + (size_t)NROWS * Dd;                // 4 MiB (frag-major)
  unsigned short* Vf = Kf + (size_t)NROWS * Dd;                // 4 MiB (frag-major, j-permuted)
  unsigned short* Op = Vf + (size_t)Bb * Dd * Ss;              // 16 MiB (bf16 partials)
  float* Lp = (float*)(Op + (size_t)NSB * NROWS * Dd);         // 256 KiB
  hipLaunchKernelGGL(prep_kern, dim3(4096 + 512 + 512), dim3(256), 0, stream,
                     Q, K, V, Qn, Kf, Vf);
  hipLaunchKernelGGL(attn_kern, dim3(1024), dim3(128), 0, stream, Qn, Kf, Vf, Op, Lp);
  hipLaunchKernelGGL(comb_kern, dim3(2048), dim3(256), 0, stream, Op, Lp, Out);
}

// Round 3
// 107.517 us; speedup vs baseline: 1.0682x; 1.0421x over previous
//
#include <hip/hip_runtime.h>
#include <stdint.h>

#define Bb 8
#define Ll 2048
#define Ss 2048
#define Dd 128
#define NSB 4
#define SCHUNK 512
#define NROWS 16384  // Bb*Ll == Bb*Ss
#define SCALE_LOG2E 92.33248261689366f  // 64 * log2(e); also the fixed softmax max

typedef __attribute__((ext_vector_type(8))) short bf16x8;
typedef __attribute__((ext_vector_type(16))) float f32x16;

__device__ __forceinline__ unsigned f2bf_pack(float a, float b) {
  unsigned ua = __float_as_uint(a); ua += 0x7fffu + ((ua >> 16) & 1u);
  unsigned ub = __float_as_uint(b); ub += 0x7fffu + ((ub >> 16) & 1u);
  return (ua >> 16) | (ub & 0xffff0000u);
}

__device__ __forceinline__ unsigned pkbf(float a, float b) {
#if __has_builtin(__builtin_amdgcn_cvt_pk_bf16_f32)
  auto r = __builtin_amdgcn_cvt_pk_bf16_f32(a, b);
  return __builtin_bit_cast(unsigned, r);
#else
  return f2bf_pack(a, b);
#endif
}

__device__ __forceinline__ void gl_lds16(const void* g, void* l) {
  __builtin_amdgcn_global_load_lds(
      (const __attribute__((address_space(1))) unsigned*)g,
      (__attribute__((address_space(3))) unsigned*)l, 16, 0, 0);
}

// Fragment-major layouts, per 32-s block = 8 slots * 1 KB = 8 KB (4096 ushort):
//  Kf slot kt, lane l=(h*32+s): K[s][d=kt*16+h*8+j], j=0..7
//  Vf slot (dblk*2+t2), lane l=(h*32+dloc): V^T[d=dblk*32+dloc][s_perm]
//    s_perm = t2*16 + 4*h + (j&3) + 8*(j>>2)  == S-MFMA C-reg order, so the
//    P B-fragment is just consecutive acc registers (no shuffles).

// ---------------- pre-pass: K/V only (Q-norm folded into attn prologue) ------
extern "C" __global__ __launch_bounds__(256)
void prep_kern(const float* __restrict__ K, const float* __restrict__ V,
               unsigned short* __restrict__ Kf, unsigned short* __restrict__ Vf) {
  __shared__ float Tf[32 * 130];
  __shared__ float Ps[32 * 8];
  __shared__ float Nr[32];
  __shared__ unsigned short Tb[32 * 128];
  const int t = threadIdx.x;
  const int bid = blockIdx.x;
  if (bid < 512) {  // K: 32-row block -> normalize -> frag-major
    const int kb = bid;
    const int b = kb & 7, sw = kb >> 3;
    const int sl = t >> 3, d0 = (t & 7) * 16;
    const float* src = K + ((size_t)(b * Ss + sw * 32 + sl)) * Dd + d0;
    float ss = 0.f;
#pragma unroll
    for (int i = 0; i < 4; ++i) {
      float4 v = *(const float4*)(src + i * 4);
      Tf[sl * 130 + d0 + i * 4 + 0] = v.x;
      Tf[sl * 130 + d0 + i * 4 + 1] = v.y;
      Tf[sl * 130 + d0 + i * 4 + 2] = v.z;
      Tf[sl * 130 + d0 + i * 4 + 3] = v.w;
      ss += v.x * v.x + v.y * v.y + v.z * v.z + v.w * v.w;
    }
    Ps[sl * 8 + (t & 7)] = ss;
    __syncthreads();
    if (t < 32) {
      float s = 0.f;
#pragma unroll
      for (int j = 0; j < 8; ++j) s += Ps[t * 8 + j];
      Nr[t] = 1.0f / fmaxf(sqrtf(s), 1e-12f);
    }
    __syncthreads();
    unsigned short* Ko = Kf + ((size_t)(b * 64 + sw)) * 4096;
#pragma unroll
    for (int p = 0; p < 2; ++p) {
      const int run = p * 256 + t;
      const int lane = run & 63, s = lane & 31, h = lane >> 5;
      const int d = (run >> 6) * 16 + h * 8;
      const float n = Nr[s];
      const float* row = &Tf[s * 130 + d];
      uint4 w;
      w.x = pkbf(row[0] * n, row[1] * n);
      w.y = pkbf(row[2] * n, row[3] * n);
      w.z = pkbf(row[4] * n, row[5] * n);
      w.w = pkbf(row[6] * n, row[7] * n);
      *(uint4*)(Ko + run * 8) = w;
    }
  } else {  // V: 32-row block -> transpose -> j-permuted frag-major
    const int vb = bid - 512;
    const int b = vb & 7, sw = vb >> 3;
    const int sl = t >> 3, d0 = (t & 7) * 16;
    const float* src = V + ((size_t)(b * Ss + sw * 32 + sl)) * Dd + d0;
#pragma unroll
    for (int i = 0; i < 4; ++i) {
      float4 v = *(const float4*)(src + i * 4);
      *(unsigned*)&Tb[sl * 128 + d0 + i * 4]     = pkbf(v.x, v.y);
      *(unsigned*)&Tb[sl * 128 + d0 + i * 4 + 2] = pkbf(v.z, v.w);
    }
    __syncthreads();
    unsigned short* Vo = Vf + ((size_t)(b * 64 + sw)) * 4096;
#pragma unroll
    for (int p = 0; p < 2; ++p) {
      const int run = p * 256 + t;
      const int vslot = run >> 6, lane = run & 63;
      const int dloc = lane & 31, h = lane >> 5;
      const int dblk = vslot >> 1, t2 = vslot & 1;
      const int d = dblk * 32 + dloc;
      unsigned short w[8];
#pragma unroll
      for (int j = 0; j < 8; ++j) {
        const int sloc = t2 * 16 + 4 * h + (j & 3) + 8 * (j >> 2);
        w[j] = Tb[sloc * 128 + d];
      }
      *(uint4*)(Vo + run * 8) = *(uint4*)w;
    }
  }
}

// ---------------- main fused attention: vmcnt-gated ring pipeline ----------
// grid 512: gid = qt*32 + b*4 + sb; 4 waves, 32 q-rows each; SCHUNK=512,
// 16 iters of 32-s tiles. 4-deep LDS ring (64 KB), staged at distance 2;
// per-iter gate = `s_waitcnt vmcnt(4); s_barrier` (raw) so the barrier
// NEVER drains in-flight prefetches (the __syncthreads vmcnt(0) stall).
// Hot loop is byte-identical to the verified 106.6 µs baseline; the only
// change is the prologue: Q rows are loaded from f32 and normalized
// in-register (lane (h,lm) owns exactly its 8x8-f32 fragment chunks; one
// shfl_xor(32) pairs the two half-row lanes), deleting the Qn round-trip.
extern "C" __global__ __launch_bounds__(256, 2)
void attn_kern(const float* __restrict__ Q,
               const unsigned short* __restrict__ Kf,
               const unsigned short* __restrict__ Vf,
               unsigned short* __restrict__ Op,
               float* __restrict__ Lp) {
  __shared__ unsigned short Kl[4][8 * 512];  // 4-ring of 8-slot (8 KB) K tiles
  __shared__ unsigned short Vl[4][8 * 512];
  const int tid = threadIdx.x, wv = tid >> 6, lane = tid & 63;
  const int lm = lane & 31, h = lane >> 5;
  const int gid = blockIdx.x;
  const int qt = gid >> 5, b = (gid >> 2) & 7, sb = gid & 3;
  const int sblk0 = sb * (SCHUNK / 32);
  const int qrow = qt * 128 + wv * 32 + lm;

  // Q prologue: load own row's fragment chunks (f32), normalize, cvt to bf16
  const float* Qr = Q + ((size_t)(b * Ll + qrow)) * Dd;
  float qv[8][8];
  float ss = 0.f;
#pragma unroll
  for (int kt = 0; kt < 8; ++kt) {
    const float* cp = Qr + kt * 16 + h * 8;
    float4 u0 = *(const float4*)cp;
    float4 u1 = *(const float4*)(cp + 4);
    qv[kt][0] = u0.x; qv[kt][1] = u0.y; qv[kt][2] = u0.z; qv[kt][3] = u0.w;
    qv[kt][4] = u1.x; qv[kt][5] = u1.y; qv[kt][6] = u1.z; qv[kt][7] = u1.w;
    ss += u0.x * u0.x + u0.y * u0.y + u0.z * u0.z + u0.w * u0.w +
          u1.x * u1.x + u1.y * u1.y + u1.z * u1.z + u1.w * u1.w;
  }
  ss += __shfl_xor(ss, 32, 64);  // combine the two half-row lanes (h=0,h=1)
  const float qinv = 1.0f / fmaxf(sqrtf(ss), 1e-12f);
  bf16x8 qf[8];
#pragma unroll
  for (int kt = 0; kt < 8; ++kt) {
    uint4 w;
    w.x = pkbf(qv[kt][0] * qinv, qv[kt][1] * qinv);
    w.y = pkbf(qv[kt][2] * qinv, qv[kt][3] * qinv);
    w.z = pkbf(qv[kt][4] * qinv, qv[kt][5] * qinv);
    w.w = pkbf(qv[kt][6] * qinv, qv[kt][7] * qinv);
    qf[kt] = __builtin_bit_cast(bf16x8, w);
  }

  const unsigned short* Kc = Kf + ((size_t)(b * 64 + sblk0)) * 4096;
  const unsigned short* Vc = Vf + ((size_t)(b * 64 + sblk0)) * 4096;

  f32x16 o[4];
#pragma unroll
  for (int i = 0; i < 4; ++i)
#pragma unroll
    for (int r = 0; r < 16; ++r) o[i][r] = 0.f;

  // stage tile t into ring slot r: 4 gl_lds16 per wave (2 K + 2 V)
  auto stage = [&](int t, int r) {
    const unsigned short* kb = Kc + (size_t)t * 4096;
    const unsigned short* vb = Vc + (size_t)t * 4096;
#pragma unroll
    for (int i = 0; i < 2; ++i) {
      const int sl = wv * 2 + i;
      gl_lds16(kb + sl * 512 + lane * 8, &Kl[r][sl * 512]);
      gl_lds16(vb + sl * 512 + lane * 8, &Vl[r][sl * 512]);
    }
  };
  stage(0, 0);
  stage(1, 1);

  float lrun = 0.f;

#pragma unroll 1
  for (int it = 0; it < 16; ++it) {
    // Gate: batch(it) complete (<=4 outstanding leaves only batch(it+1)
    // in flight), then converge. No vmcnt(0) drain except the final tile.
    if (it < 15)
      asm volatile("s_waitcnt vmcnt(4)\n\ts_barrier" ::: "memory");
    else
      asm volatile("s_waitcnt vmcnt(0)\n\ts_barrier" ::: "memory");
    const int r = it & 3;
    if (it + 2 < 16) stage(it + 2, (it + 2) & 3);

    // S^T = K · Q^T  (M=s 32, N=m 32, K=d 8x16)
    f32x16 acc;
#pragma unroll
    for (int rr = 0; rr < 16; ++rr) acc[rr] = 0.f;
#pragma unroll
    for (int kt = 0; kt < 8; ++kt) {
      bf16x8 kf = *(const bf16x8*)&Kl[r][kt * 512 + lane * 8];
      acc = __builtin_amdgcn_mfma_f32_32x32x16_bf16(kf, qf[kt], acc, 0, 0, 0);
    }
    // fixed-max softmax; P B-frag = consecutive acc regs (j-permuted Vf)
#pragma unroll
    for (int t2 = 0; t2 < 2; ++t2) {
      float p[8];
#pragma unroll
      for (int j = 0; j < 8; ++j)
        p[j] = __builtin_amdgcn_exp2f(
            __builtin_fmaf(acc[t2 * 8 + j], SCALE_LOG2E, -SCALE_LOG2E));
      lrun += ((p[0] + p[1]) + (p[2] + p[3])) + ((p[4] + p[5]) + (p[6] + p[7]));
      uint4 fr;
      fr.x = pkbf(p[0], p[1]);
      fr.y = pkbf(p[2], p[3]);
      fr.z = pkbf(p[4], p[5]);
      fr.w = pkbf(p[6], p[7]);
      bf16x8 pf = __builtin_bit_cast(bf16x8, fr);
      // O^T += V^T · P^T  (M=d 4x32, N=m 32, K=s 16, s-order pre-permuted)
#pragma unroll
      for (int dblk = 0; dblk < 4; ++dblk) {
        bf16x8 vf = *(const bf16x8*)&Vl[r][(dblk * 2 + t2) * 512 + lane * 8];
        o[dblk] = __builtin_amdgcn_mfma_f32_32x32x16_bf16(vf, pf, o[dblk], 0, 0, 0);
      }
    }
  }

  // epilogue: partial (unnormalized) O bf16 + per-row l (shared fixed max)
  const float lt = lrun + __shfl_xor(lrun, 32, 64);
  unsigned short* Ob = Op + ((size_t)sb * NROWS + b * Ll + qrow) * Dd;
#pragma unroll
  for (int dblk = 0; dblk < 4; ++dblk)
#pragma unroll
    for (int g = 0; g < 4; ++g) {
      uint2 w;
      w.x = pkbf(o[dblk][g * 4 + 0], o[dblk][g * 4 + 1]);
      w.y = pkbf(o[dblk][g * 4 + 2], o[dblk][g * 4 + 3]);
      *(uint2*)(Ob + dblk * 32 + g * 8 + h * 4) = w;  // d = 32*dblk + 8*g + 4*h
    }
  if (h == 0) Lp[sb * NROWS + b * Ll + qrow] = lt;
}

// ---------------- combine the NSB S-chunk partials (pure sum: shared max) ---
extern "C" __global__ __launch_bounds__(256)
void comb_kern(const unsigned short* __restrict__ Op,
               const float* __restrict__ Lp, float* __restrict__ Out) {
  const int idx = blockIdx.x * 256 + threadIdx.x;  // one thread per 8 d
  const int row = idx >> 4;
  const int dof = (idx & 15) * 8;
  float den = 0.f;
#pragma unroll
  for (int s = 0; s < NSB; ++s) den += Lp[s * NROWS + row];
  float a[8] = {0.f, 0.f, 0.f, 0.f, 0.f, 0.f, 0.f, 0.f};
#pragma unroll
  for (int s = 0; s < NSB; ++s) {
    uint4 v = *(const uint4*)(Op + ((size_t)s * NROWS + row) * Dd + dof);
    a[0] += __uint_as_float(v.x << 16);
    a[1] += __uint_as_float(v.x & 0xffff0000u);
    a[2] += __uint_as_float(v.y << 16);
    a[3] += __uint_as_float(v.y & 0xffff0000u);
    a[4] += __uint_as_float(v.z << 16);
    a[5] += __uint_as_float(v.z & 0xffff0000u);
    a[6] += __uint_as_float(v.w << 16);
    a[7] += __uint_as_float(v.w & 0xffff0000u);
  }
  const float inv = 1.f / den;
  float4 r0; r0.x = a[0] * inv; r0.y = a[1] * inv; r0.z = a[2] * inv; r0.w = a[3] * inv;
  float4 r1; r1.x = a[4] * inv; r1.y = a[5] * inv; r1.z = a[6] * inv; r1.w = a[7] * inv;
  float* op = Out + (size_t)row * Dd + dof;
  *(float4*)op = r0;
  *(float4*)(op + 4) = r1;
}

extern "C" void kernel_launch(void* const* d_in, const int* in_sizes, int n_in,
                              void* d_out, int out_size, void* d_ws, size_t ws_size,
                              hipStream_t stream) {
  const float* Q = (const float*)d_in[0];
  const float* K = (const float*)d_in[1];
  const float* V = (const float*)d_in[2];
  float* Out = (float*)d_out;
  unsigned short* Kf = (unsigned short*)d_ws;                  // 4 MiB (frag-major)
  unsigned short* Vf = Kf + (size_t)NROWS * Dd;                // 4 MiB (frag-major, j-permuted)
  unsigned short* Op = Vf + (size_t)Bb * Dd * Ss;              // 16 MiB (bf16 partials)
  float* Lp = (float*)(Op + (size_t)NSB * NROWS * Dd);         // 256 KiB
  hipLaunchKernelGGL(prep_kern, dim3(1024), dim3(256), 0, stream, K, V, Kf, Vf);
  hipLaunchKernelGGL(attn_kern, dim3(512), dim3(256), 0, stream, Q, Kf, Vf, Op, Lp);
  hipLaunchKernelGGL(comb_kern, dim3(1024), dim3(256), 0, stream, Op, Lp, Out);
}

// Round 4
// 106.001 us; speedup vs baseline: 1.0834x; 1.0143x over previous
//
#include <hip/hip_runtime.h>
#include <stdint.h>

#define Bb 8
#define Ll 2048
#define Ss 2048
#define Dd 128
#define NSB 4
#define SCHUNK 512
#define NROWS 16384  // Bb*Ll == Bb*Ss
#define SCALE_LOG2E 92.33248261689366f  // 64 * log2(e); also the fixed softmax max

typedef __attribute__((ext_vector_type(8))) short bf16x8;
typedef __attribute__((ext_vector_type(16))) float f32x16;

__device__ __forceinline__ unsigned f2bf_pack(float a, float b) {
  unsigned ua = __float_as_uint(a); ua += 0x7fffu + ((ua >> 16) & 1u);
  unsigned ub = __float_as_uint(b); ub += 0x7fffu + ((ub >> 16) & 1u);
  return (ua >> 16) | (ub & 0xffff0000u);
}

__device__ __forceinline__ unsigned pkbf(float a, float b) {
#if __has_builtin(__builtin_amdgcn_cvt_pk_bf16_f32)
  auto r = __builtin_amdgcn_cvt_pk_bf16_f32(a, b);
  return __builtin_bit_cast(unsigned, r);
#else
  return f2bf_pack(a, b);
#endif
}

__device__ __forceinline__ void gl_lds16(const void* g, void* l) {
  __builtin_amdgcn_global_load_lds(
      (const __attribute__((address_space(1))) unsigned*)g,
      (__attribute__((address_space(3))) unsigned*)l, 16, 0, 0);
}

// Fragment-major layouts, per 32-s block = 8 slots * 1 KB = 8 KB (4096 ushort):
//  Kf slot kt, lane l=(h*32+s): K[s][d=kt*16+h*8+j], j=0..7
//  Vf slot (dblk*2+t2), lane l=(h*32+dloc): V^T[d=dblk*32+dloc][s_perm]
//    s_perm = t2*16 + 4*h + (j&3) + 8*(j>>2)  == S-MFMA C-reg order, so the
//    P B-fragment is just consecutive acc registers (no shuffles).

// ---------------- pre-pass: K/V only (Q-norm folded into attn prologue) ------
extern "C" __global__ __launch_bounds__(256)
void prep_kern(const float* __restrict__ K, const float* __restrict__ V,
               unsigned short* __restrict__ Kf, unsigned short* __restrict__ Vf) {
  __shared__ float Tf[32 * 130];
  __shared__ float Ps[32 * 8];
  __shared__ float Nr[32];
  __shared__ unsigned short Tb[32 * 128];
  const int t = threadIdx.x;
  const int bid = blockIdx.x;
  if (bid < 512) {  // K: 32-row block -> normalize -> frag-major
    const int kb = bid;
    const int b = kb & 7, sw = kb >> 3;
    const int sl = t >> 3, d0 = (t & 7) * 16;
    const float* src = K + ((size_t)(b * Ss + sw * 32 + sl)) * Dd + d0;
    float ss = 0.f;
#pragma unroll
    for (int i = 0; i < 4; ++i) {
      float4 v = *(const float4*)(src + i * 4);
      Tf[sl * 130 + d0 + i * 4 + 0] = v.x;
      Tf[sl * 130 + d0 + i * 4 + 1] = v.y;
      Tf[sl * 130 + d0 + i * 4 + 2] = v.z;
      Tf[sl * 130 + d0 + i * 4 + 3] = v.w;
      ss += v.x * v.x + v.y * v.y + v.z * v.z + v.w * v.w;
    }
    Ps[sl * 8 + (t & 7)] = ss;
    __syncthreads();
    if (t < 32) {
      float s = 0.f;
#pragma unroll
      for (int j = 0; j < 8; ++j) s += Ps[t * 8 + j];
      Nr[t] = 1.0f / fmaxf(sqrtf(s), 1e-12f);
    }
    __syncthreads();
    unsigned short* Ko = Kf + ((size_t)(b * 64 + sw)) * 4096;
#pragma unroll
    for (int p = 0; p < 2; ++p) {
      const int run = p * 256 + t;
      const int lane = run & 63, s = lane & 31, h = lane >> 5;
      const int d = (run >> 6) * 16 + h * 8;
      const float n = Nr[s];
      const float* row = &Tf[s * 130 + d];
      uint4 w;
      w.x = pkbf(row[0] * n, row[1] * n);
      w.y = pkbf(row[2] * n, row[3] * n);
      w.z = pkbf(row[4] * n, row[5] * n);
      w.w = pkbf(row[6] * n, row[7] * n);
      *(uint4*)(Ko + run * 8) = w;
    }
  } else {  // V: 32-row block -> transpose -> j-permuted frag-major
    const int vb = bid - 512;
    const int b = vb & 7, sw = vb >> 3;
    const int sl = t >> 3, d0 = (t & 7) * 16;
    const float* src = V + ((size_t)(b * Ss + sw * 32 + sl)) * Dd + d0;
#pragma unroll
    for (int i = 0; i < 4; ++i) {
      float4 v = *(const float4*)(src + i * 4);
      *(unsigned*)&Tb[sl * 128 + d0 + i * 4]     = pkbf(v.x, v.y);
      *(unsigned*)&Tb[sl * 128 + d0 + i * 4 + 2] = pkbf(v.z, v.w);
    }
    __syncthreads();
    unsigned short* Vo = Vf + ((size_t)(b * 64 + sw)) * 4096;
#pragma unroll
    for (int p = 0; p < 2; ++p) {
      const int run = p * 256 + t;
      const int vslot = run >> 6, lane = run & 63;
      const int dloc = lane & 31, h = lane >> 5;
      const int dblk = vslot >> 1, t2 = vslot & 1;
      const int d = dblk * 32 + dloc;
      unsigned short w[8];
#pragma unroll
      for (int j = 0; j < 8; ++j) {
        const int sloc = t2 * 16 + 4 * h + (j & 3) + 8 * (j >> 2);
        w[j] = Tb[sloc * 128 + d];
      }
      *(uint4*)(Vo + run * 8) = *(uint4*)w;
    }
  }
}

// ---------------- main fused attention: vmcnt-gated ring + T15 pipeline ----
// grid 512: gid = qt*32 + b*4 + sb; 4 waves, 32 q-rows each; SCHUNK=512,
// 16 tiles of 32-s. 4-deep LDS ring (64 KB), staged at distance 2; per-body
// gate = `s_waitcnt vmcnt(4); s_barrier` (never drains in-flight prefetch).
// T15 software pipeline (1-tile shift): body it = gate(tile it) ->
// stage(it+2) -> QK(it)->acc_cur INTERLEAVED with SM+PV(it-1) from acc_prev.
// QK's MFMA chain and SM's VALU chain are independent -> scheduler co-issues
// matrix + vector pipes within one wave instead of serializing phases.
// acc ping-pong is static (accA/accB, 2-body unroll) to avoid scratch.
extern "C" __global__ __launch_bounds__(256, 2)
void attn_kern(const float* __restrict__ Q,
               const unsigned short* __restrict__ Kf,
               const unsigned short* __restrict__ Vf,
               unsigned short* __restrict__ Op,
               float* __restrict__ Lp) {
  __shared__ unsigned short Kl[4][8 * 512];  // 4-ring of 8-slot (8 KB) K tiles
  __shared__ unsigned short Vl[4][8 * 512];
  const int tid = threadIdx.x, wv = tid >> 6, lane = tid & 63;
  const int lm = lane & 31, h = lane >> 5;
  const int gid = blockIdx.x;
  const int qt = gid >> 5, b = (gid >> 2) & 7, sb = gid & 3;
  const int sblk0 = sb * (SCHUNK / 32);
  const int qrow = qt * 128 + wv * 32 + lm;

  // Q prologue: load own row's fragment chunks (f32), normalize, cvt to bf16.
  // All Q loads are consumed (vmcnt-drained) before the first stage() below,
  // so the gate's vmcnt(4) counts only gl_lds staging ops.
  const float* Qr = Q + ((size_t)(b * Ll + qrow)) * Dd;
  float qv[8][8];
  float ss = 0.f;
#pragma unroll
  for (int kt = 0; kt < 8; ++kt) {
    const float* cp = Qr + kt * 16 + h * 8;
    float4 u0 = *(const float4*)cp;
    float4 u1 = *(const float4*)(cp + 4);
    qv[kt][0] = u0.x; qv[kt][1] = u0.y; qv[kt][2] = u0.z; qv[kt][3] = u0.w;
    qv[kt][4] = u1.x; qv[kt][5] = u1.y; qv[kt][6] = u1.z; qv[kt][7] = u1.w;
    ss += u0.x * u0.x + u0.y * u0.y + u0.z * u0.z + u0.w * u0.w +
          u1.x * u1.x + u1.y * u1.y + u1.z * u1.z + u1.w * u1.w;
  }
  ss += __shfl_xor(ss, 32, 64);  // combine the two half-row lanes (h=0,h=1)
  const float qinv = 1.0f / fmaxf(sqrtf(ss), 1e-12f);
  bf16x8 qf[8];
#pragma unroll
  for (int kt = 0; kt < 8; ++kt) {
    uint4 w;
    w.x = pkbf(qv[kt][0] * qinv, qv[kt][1] * qinv);
    w.y = pkbf(qv[kt][2] * qinv, qv[kt][3] * qinv);
    w.z = pkbf(qv[kt][4] * qinv, qv[kt][5] * qinv);
    w.w = pkbf(qv[kt][6] * qinv, qv[kt][7] * qinv);
    qf[kt] = __builtin_bit_cast(bf16x8, w);
  }

  const unsigned short* Kc = Kf + ((size_t)(b * 64 + sblk0)) * 4096;
  const unsigned short* Vc = Vf + ((size_t)(b * 64 + sblk0)) * 4096;

  f32x16 o[4];
#pragma unroll
  for (int i = 0; i < 4; ++i)
#pragma unroll
    for (int r = 0; r < 16; ++r) o[i][r] = 0.f;

  // stage tile t into ring slot r: 4 gl_lds16 per wave (2 K + 2 V)
  auto stage = [&](int t, int r) {
    const unsigned short* kb = Kc + (size_t)t * 4096;
    const unsigned short* vb = Vc + (size_t)t * 4096;
#pragma unroll
    for (int i = 0; i < 2; ++i) {
      const int sl = wv * 2 + i;
      gl_lds16(kb + sl * 512 + lane * 8, &Kl[r][sl * 512]);
      gl_lds16(vb + sl * 512 + lane * 8, &Vl[r][sl * 512]);
    }
  };

  float lrun = 0.f;
  f32x16 accA, accB;

  // QK(tile in ring slot `slot`) -> a
  auto qk = [&](f32x16& a, int slot) {
#pragma unroll
    for (int rr = 0; rr < 16; ++rr) a[rr] = 0.f;
#pragma unroll
    for (int kt = 0; kt < 8; ++kt) {
      bf16x8 kf = *(const bf16x8*)&Kl[slot][kt * 512 + lane * 8];
      a = __builtin_amdgcn_mfma_f32_32x32x16_bf16(kf, qf[kt], a, 0, 0, 0);
    }
  };
  // softmax + PV for the tile whose scores are in `a`, V in ring slot `slot`
  auto smpv = [&](const f32x16& a, int slot) {
#pragma unroll
    for (int t2 = 0; t2 < 2; ++t2) {
      float p[8];
#pragma unroll
      for (int j = 0; j < 8; ++j)
        p[j] = __builtin_amdgcn_exp2f(
            __builtin_fmaf(a[t2 * 8 + j], SCALE_LOG2E, -SCALE_LOG2E));
      lrun += ((p[0] + p[1]) + (p[2] + p[3])) + ((p[4] + p[5]) + (p[6] + p[7]));
      uint4 fr;
      fr.x = pkbf(p[0], p[1]);
      fr.y = pkbf(p[2], p[3]);
      fr.z = pkbf(p[4], p[5]);
      fr.w = pkbf(p[6], p[7]);
      bf16x8 pf = __builtin_bit_cast(bf16x8, fr);
#pragma unroll
      for (int dblk = 0; dblk < 4; ++dblk) {
        bf16x8 vf = *(const bf16x8*)&Vl[slot][(dblk * 2 + t2) * 512 + lane * 8];
        o[dblk] = __builtin_amdgcn_mfma_f32_32x32x16_bf16(vf, pf, o[dblk], 0, 0, 0);
      }
    }
  };

  stage(0, 0);
  stage(1, 1);

  // body 0: gate tile 0 (outstanding = batches 0,1 -> vmcnt(4) drains batch 0)
  asm volatile("s_waitcnt vmcnt(4)\n\ts_barrier" ::: "memory");
  stage(2, 2);
  qk(accA, 0);

  // bodies 1..14: gate(tile it) -> stage(it+2) -> QK(it) || SM+PV(it-1).
  // Invariant at body it's gate: outstanding = batches {it, it+1} (8 per-wave
  // ops) -> vmcnt(4) completes batch it, leaves it+1 in flight.
#pragma unroll 1
  for (int i2 = 0; i2 < 7; ++i2) {
    const int itO = 2 * i2 + 1;  // odd body: QK->accB, SM/PV from accA
    asm volatile("s_waitcnt vmcnt(4)\n\ts_barrier" ::: "memory");
    stage(itO + 2, (itO + 2) & 3);
    qk(accB, itO & 3);
    smpv(accA, (itO - 1) & 3);
    const int itE = itO + 1;     // even body: QK->accA, SM/PV from accB
    asm volatile("s_waitcnt vmcnt(4)\n\ts_barrier" ::: "memory");
    if (itE + 2 <= 15) stage(itE + 2, (itE + 2) & 3);
    qk(accA, itE & 3);
    smpv(accB, (itE - 1) & 3);
  }

  // body 15: only batch 15 outstanding -> full drain
  asm volatile("s_waitcnt vmcnt(0)\n\ts_barrier" ::: "memory");
  qk(accB, 15 & 3);
  smpv(accA, 14 & 3);
  // tail body 16: finish tile 15
  smpv(accB, 15 & 3);

  // epilogue: partial (unnormalized) O bf16 + per-row l (shared fixed max)
  const float lt = lrun + __shfl_xor(lrun, 32, 64);
  unsigned short* Ob = Op + ((size_t)sb * NROWS + b * Ll + qrow) * Dd;
#pragma unroll
  for (int dblk = 0; dblk < 4; ++dblk)
#pragma unroll
    for (int g = 0; g < 4; ++g) {
      uint2 w;
      w.x = pkbf(o[dblk][g * 4 + 0], o[dblk][g * 4 + 1]);
      w.y = pkbf(o[dblk][g * 4 + 2], o[dblk][g * 4 + 3]);
      *(uint2*)(Ob + dblk * 32 + g * 8 + h * 4) = w;  // d = 32*dblk + 8*g + 4*h
    }
  if (h == 0) Lp[sb * NROWS + b * Ll + qrow] = lt;
}

// ---------------- combine the NSB S-chunk partials (pure sum: shared max) ---
extern "C" __global__ __launch_bounds__(256)
void comb_kern(const unsigned short* __restrict__ Op,
               const float* __restrict__ Lp, float* __restrict__ Out) {
  const int idx = blockIdx.x * 256 + threadIdx.x;  // one thread per 8 d
  const int row = idx >> 4;
  const int dof = (idx & 15) * 8;
  float den = 0.f;
#pragma unroll
  for (int s = 0; s < NSB; ++s) den += Lp[s * NROWS + row];
  float a[8] = {0.f, 0.f, 0.f, 0.f, 0.f, 0.f, 0.f, 0.f};
#pragma unroll
  for (int s = 0; s < NSB; ++s) {
    uint4 v = *(const uint4*)(Op + ((size_t)s * NROWS + row) * Dd + dof);
    a[0] += __uint_as_float(v.x << 16);
    a[1] += __uint_as_float(v.x & 0xffff0000u);
    a[2] += __uint_as_float(v.y << 16);
    a[3] += __uint_as_float(v.y & 0xffff0000u);
    a[4] += __uint_as_float(v.z << 16);
    a[5] += __uint_as_float(v.z & 0xffff0000u);
    a[6] += __uint_as_float(v.w << 16);
    a[7] += __uint_as_float(v.w & 0xffff0000u);
  }
  const float inv = 1.f / den;
  float4 r0; r0.x = a[0] * inv; r0.y = a[1] * inv; r0.z = a[2] * inv; r0.w = a[3] * inv;
  float4 r1; r1.x = a[4] * inv; r1.y = a[5] * inv; r1.z = a[6] * inv; r1.w = a[7] * inv;
  float* op = Out + (size_t)row * Dd + dof;
  *(float4*)op = r0;
  *(float4*)(op + 4) = r1;
}

extern "C" void kernel_launch(void* const* d_in, const int* in_sizes, int n_in,
                              void* d_out, int out_size, void* d_ws, size_t ws_size,
                              hipStream_t stream) {
  const float* Q = (const float*)d_in[0];
  const float* K = (const float*)d_in[1];
  const float* V = (const float*)d_in[2];
  float* Out = (float*)d_out;
  unsigned short* Kf = (unsigned short*)d_ws;                  // 4 MiB (frag-major)
  unsigned short* Vf = Kf + (size_t)NROWS * Dd;                // 4 MiB (frag-major, j-permuted)
  unsigned short* Op = Vf + (size_t)Bb * Dd * Ss;              // 16 MiB (bf16 partials)
  float* Lp = (float*)(Op + (size_t)NSB * NROWS * Dd);         // 256 KiB
  hipLaunchKernelGGL(prep_kern, dim3(1024), dim3(256), 0, stream, K, V, Kf, Vf);
  hipLaunchKernelGGL(attn_kern, dim3(512), dim3(256), 0, stream, Q, Kf, Vf, Op, Lp);
  hipLaunchKernelGGL(comb_kern, dim3(1024), dim3(256), 0, stream, Op, Lp, Out);
}